// Round 3
// baseline (588.736 us; speedup 1.0000x reference)
//
#include <hip/hip_runtime.h>
#include <hip/hip_bf16.h>

// LightGCNConv: out[dst] = sum_e w[e] * x[src_e], N=100000, d=64, E=1250000.
//
// R1: 80M fp32 device atomics -> 291G atomics/s bound (350us).
// R2: exact-CSR pipeline; k_fill's random 8B scatter got 8x write amplification
//     (WRITE_SIZE 80MB for 10MB logical) = 90us; k_gather 88us. Total 295us.
// R3: coarse buckets (64 nodes = 1 bucket, K=1563):
//     - k_bhist/k_bscan: tiny 1563-entry histogram + single-WG scan.
//     - k_bfill: block-reserved contiguous runs per bucket -> near-line-granular
//       writes (amp ~2-3x instead of 8x). Payload packs src|dst_local + weight.
//     - k_bgather: one WG per bucket, 16KB LDS fp32 accumulator (8 WG/CU),
//       ds_add_f32 accumulation, 4-deep unrolled random row loads, one
//       contiguous 16KB streaming writeback. No per-node CSR at all.

#define N_NODES   100000
#define N_FEAT    64
#define NPB       64                      // nodes per bucket
#define K_BUCKETS ((N_NODES + NPB - 1) / NPB)   // 1563
#define FCHUNK    4096                    // edges per k_bfill block

// ---- bucket histogram (LDS-aggregated) ----
__global__ __launch_bounds__(256) void k_bhist(
    const int* __restrict__ ei, int* __restrict__ bcur, int E) {
    __shared__ int h[K_BUCKETS];
    int t = threadIdx.x;
    for (int b = t; b < K_BUCKETS; b += 256) h[b] = 0;
    __syncthreads();
    int e0 = blockIdx.x * FCHUNK;
    #pragma unroll
    for (int k = 0; k < FCHUNK / 256; ++k) {
        int e = e0 + k * 256 + t;
        if (e < E) atomicAdd(&h[ei[E + e] >> 6], 1);
    }
    __syncthreads();
    for (int b = t; b < K_BUCKETS; b += 256) {
        int c = h[b];
        if (c) atomicAdd(&bcur[b], c);
    }
}

// ---- single-WG exclusive scan of 1563 counts -> boffs; bcur = cursor ----
#define VPT 7   // 256*7 = 1792 >= K_BUCKETS
__global__ __launch_bounds__(256) void k_bscan(
    int* __restrict__ bcur, int* __restrict__ boffs) {
    __shared__ int sdata[256];
    int t = threadIdx.x;
    int vals[VPT];
    int s = 0;
    #pragma unroll
    for (int k = 0; k < VPT; ++k) {
        int i = t * VPT + k;
        vals[k] = (i < K_BUCKETS) ? bcur[i] : 0;
        s += vals[k];
    }
    sdata[t] = s; __syncthreads();
    for (int off = 1; off < 256; off <<= 1) {
        int v = (t >= off) ? sdata[t - off] : 0;
        __syncthreads();
        if (t >= off) sdata[t] += v;
        __syncthreads();
    }
    int run = (t == 0) ? 0 : sdata[t - 1];
    #pragma unroll
    for (int k = 0; k < VPT; ++k) {
        int i = t * VPT + k;
        if (i < K_BUCKETS) { boffs[i] = run; bcur[i] = run; }
        run += vals[k];
    }
    if (t == 255) boffs[K_BUCKETS] = run;   // == E
}

// ---- fill: block-reserved contiguous runs per bucket ----
__global__ __launch_bounds__(256) void k_bfill(
    const int* __restrict__ ei, const float* __restrict__ w,
    int* __restrict__ bcur, int2* __restrict__ staging, int E) {
    __shared__ int h[K_BUCKETS];
    int t = threadIdx.x;
    for (int b = t; b < K_BUCKETS; b += 256) h[b] = 0;
    __syncthreads();
    int e0 = blockIdx.x * FCHUNK;
    #pragma unroll
    for (int k = 0; k < FCHUNK / 256; ++k) {
        int e = e0 + k * 256 + t;
        if (e < E) atomicAdd(&h[ei[E + e] >> 6], 1);
    }
    __syncthreads();
    // reserve a contiguous run per (block,bucket); h[b] becomes absolute cursor
    for (int b = t; b < K_BUCKETS; b += 256) {
        int c = h[b];
        h[b] = c ? atomicAdd(&bcur[b], c) : 0;
    }
    __syncthreads();
    #pragma unroll
    for (int k = 0; k < FCHUNK / 256; ++k) {
        int e = e0 + k * 256 + t;
        if (e < E) {
            int dst = ei[E + e];
            int b = dst >> 6;
            int slot = atomicAdd(&h[b], 1);            // LDS atomic
            staging[slot] = make_int2(ei[e] | ((dst & 63) << 17),
                                      __float_as_int(w[e]));
        }
    }
}

// ---- fused gather + LDS accumulate + streaming writeback ----
__global__ __launch_bounds__(256) void k_bgather(
    const float* __restrict__ x, const int* __restrict__ boffs,
    const int2* __restrict__ staging, float* __restrict__ out, int total_out) {
    __shared__ float acc[NPB * N_FEAT];   // 16 KB
    int t = threadIdx.x;
    #pragma unroll
    for (int i = t; i < NPB * N_FEAT; i += 256) acc[i] = 0.f;
    __syncthreads();

    int beg = boffs[blockIdx.x], end = boffs[blockIdx.x + 1];
    int wid  = __builtin_amdgcn_readfirstlane(threadIdx.x) >> 6;  // wave-uniform
    int lane = threadIdx.x & 63;

    int j = beg + wid;
    for (; j + 12 < end; j += 16) {
        int2 p0 = staging[j];
        int2 p1 = staging[j + 4];
        int2 p2 = staging[j + 8];
        int2 p3 = staging[j + 12];
        float v0 = __int_as_float(p0.y) * x[(size_t)(p0.x & 0x1FFFF) * N_FEAT + lane];
        float v1 = __int_as_float(p1.y) * x[(size_t)(p1.x & 0x1FFFF) * N_FEAT + lane];
        float v2 = __int_as_float(p2.y) * x[(size_t)(p2.x & 0x1FFFF) * N_FEAT + lane];
        float v3 = __int_as_float(p3.y) * x[(size_t)(p3.x & 0x1FFFF) * N_FEAT + lane];
        atomicAdd(&acc[((p0.x >> 17) << 6) + lane], v0);
        atomicAdd(&acc[((p1.x >> 17) << 6) + lane], v1);
        atomicAdd(&acc[((p2.x >> 17) << 6) + lane], v2);
        atomicAdd(&acc[((p3.x >> 17) << 6) + lane], v3);
    }
    for (; j < end; j += 4) {
        int2 p = staging[j];
        float v = __int_as_float(p.y) * x[(size_t)(p.x & 0x1FFFF) * N_FEAT + lane];
        atomicAdd(&acc[((p.x >> 17) << 6) + lane], v);
    }
    __syncthreads();

    size_t base = (size_t)blockIdx.x * (NPB * N_FEAT);
    int lim = NPB * N_FEAT;
    if ((int)(total_out - base) < lim) lim = (int)(total_out - base);
    for (int i = t; i < lim; i += 256) out[base + i] = acc[i];
}

// ---- fallback (R1 atomic scatter) ----
__global__ __launch_bounds__(256) void gnn_scatter_kernel(
    const float* __restrict__ x, const int* __restrict__ ei,
    const float* __restrict__ w, float* __restrict__ out, int E) {
    int e = blockIdx.x * 4 + (threadIdx.x >> 6);
    int lane = threadIdx.x & 63;
    if (e >= E) return;
    float v = w[e] * x[(size_t)ei[e] * N_FEAT + lane];
    atomicAdd(&out[(size_t)ei[E + e] * N_FEAT + lane], v);
}

static inline size_t align16(size_t v) { return (v + 15) & ~(size_t)15; }

extern "C" void kernel_launch(void* const* d_in, const int* in_sizes, int n_in,
                              void* d_out, int out_size, void* d_ws, size_t ws_size,
                              hipStream_t stream) {
    const float* x   = (const float*)d_in[0];
    const int*   ei  = (const int*)d_in[1];
    const float* w   = (const float*)d_in[2];
    float*       out = (float*)d_out;
    const int E = in_sizes[2];

    size_t off_bcur  = 0;
    size_t off_boffs = align16(off_bcur + (size_t)K_BUCKETS * 4);
    size_t off_stg   = align16(off_boffs + (size_t)(K_BUCKETS + 1) * 4);
    size_t need      = off_stg + (size_t)E * 8;

    if (ws_size < need) {
        hipMemsetAsync(d_out, 0, (size_t)out_size * sizeof(float), stream);
        gnn_scatter_kernel<<<(E + 3) / 4, 256, 0, stream>>>(x, ei, w, out, E);
        return;
    }

    char* ws   = (char*)d_ws;
    int*  bcur = (int*)(ws + off_bcur);
    int*  boffs = (int*)(ws + off_boffs);
    int2* stg  = (int2*)(ws + off_stg);

    const int fill_blocks = (E + FCHUNK - 1) / FCHUNK;   // 306

    hipMemsetAsync(bcur, 0, (size_t)K_BUCKETS * 4, stream);
    k_bhist<<<fill_blocks, 256, 0, stream>>>(ei, bcur, E);
    k_bscan<<<1, 256, 0, stream>>>(bcur, boffs);
    k_bfill<<<fill_blocks, 256, 0, stream>>>(ei, w, bcur, stg, E);
    k_bgather<<<K_BUCKETS, 256, 0, stream>>>(x, boffs, stg, out, out_size);
    // no out memset needed: k_bgather writes every output element exactly once
}

// Round 4
// 200.344 us; speedup vs baseline: 2.9386x; 2.9386x over previous
//
#include <hip/hip_runtime.h>
#include <hip/hip_bf16.h>

// LightGCNConv: out[dst] = sum_e w[e] * x[src_e], N=100000, d=64, E=1250000.
//
// R1: 80M fp32 device atomics -> 275us (atomic-rate bound, WRITE 320MB).
// R2: exact CSR; k_fill random 8B scatter -> 8x write amp (80MB, 90us);
//     k_gather (1 wave/node, reg accumulate) 88us. Total 295us.
// R3: fused LDS-accumulator gather with 1563 blocks -> 471us. Latency-starved
//     (6 blk/CU) + LDS fp32 atomic contention. REVERTED.
// R4: keep R2's gather; rebuild CSR with L2-resident phases:
//     k_chist/k_cscan: 391-bucket histogram + 1-block scan (tiny).
//     k_cbin:  append edges into 391 coarse buckets (256 nodes each) with
//              block-reserved runs (~168B contiguous) -> no write amp.
//     k_csort: 1 block/bucket: payload -> LDS (32KB), 256-entry hist+scan,
//              in-place scatter to exact CSR order (random writes confined to
//              ~26KB L2-resident window); emits exact per-node offs for free.
//     k_gather: R2 structure, 4-deep unroll.

#define N_NODES   100000
#define N_FEAT    64
#define BSH       8
#define NPB       (1 << BSH)                       // 256 nodes per bucket
#define KB        ((N_NODES + NPB - 1) >> BSH)     // 391 buckets
#define FCHUNK    8192                             // edges per bin/hist block
#define SORT_CAP  4096                             // LDS payload slots (32KB)

// ---- coarse histogram ----
__global__ __launch_bounds__(256) void k_chist(
    const int* __restrict__ ei, int* __restrict__ bcur, int E) {
    __shared__ int h[KB];
    int t = threadIdx.x;
    for (int b = t; b < KB; b += 256) h[b] = 0;
    __syncthreads();
    int e0 = blockIdx.x * FCHUNK;
    #pragma unroll
    for (int k = 0; k < FCHUNK / 256; ++k) {
        int e = e0 + k * 256 + t;
        if (e < E) atomicAdd(&h[ei[E + e] >> BSH], 1);
    }
    __syncthreads();
    for (int b = t; b < KB; b += 256) if (h[b]) atomicAdd(&bcur[b], h[b]);
}

// ---- single-block exclusive scan of KB counts; bcur becomes append cursor ----
__global__ __launch_bounds__(256) void k_cscan(
    int* __restrict__ bcur, int* __restrict__ boffs) {
    __shared__ int sdata[256];
    int t = threadIdx.x;
    int i0 = 2 * t, i1 = 2 * t + 1;
    int v0 = (i0 < KB) ? bcur[i0] : 0;
    int v1 = (i1 < KB) ? bcur[i1] : 0;
    sdata[t] = v0 + v1; __syncthreads();
    for (int off = 1; off < 256; off <<= 1) {
        int v = (t >= off) ? sdata[t - off] : 0;
        __syncthreads();
        if (t >= off) sdata[t] += v;
        __syncthreads();
    }
    int run = (t == 0) ? 0 : sdata[t - 1];
    if (i0 < KB) { boffs[i0] = run; bcur[i0] = run; }
    run += v0;
    if (i1 < KB) { boffs[i1] = run; bcur[i1] = run; }
    if (t == 255) boffs[KB] = sdata[255];   // == E
}

// ---- bin: block-reserved contiguous runs per coarse bucket ----
__global__ __launch_bounds__(256) void k_cbin(
    const int* __restrict__ ei, const float* __restrict__ w,
    int* __restrict__ bcur, int2* __restrict__ stg, int E) {
    __shared__ int h[KB];
    int t = threadIdx.x;
    for (int b = t; b < KB; b += 256) h[b] = 0;
    __syncthreads();
    int e0 = blockIdx.x * FCHUNK;
    #pragma unroll
    for (int k = 0; k < FCHUNK / 256; ++k) {
        int e = e0 + k * 256 + t;
        if (e < E) atomicAdd(&h[ei[E + e] >> BSH], 1);
    }
    __syncthreads();
    for (int b = t; b < KB; b += 256) {
        int c = h[b];
        h[b] = c ? atomicAdd(&bcur[b], c) : 0;   // absolute cursor
    }
    __syncthreads();
    #pragma unroll
    for (int k = 0; k < FCHUNK / 256; ++k) {
        int e = e0 + k * 256 + t;
        if (e < E) {
            int dst = ei[E + e];
            int slot = atomicAdd(&h[dst >> BSH], 1);      // LDS int atomic
            stg[slot] = make_int2(ei[e] | ((dst & (NPB - 1)) << 17),
                                  __float_as_int(w[e]));
        }
    }
}

// ---- sort within bucket (L2-resident in-place scatter) + exact offs ----
__global__ __launch_bounds__(256) void k_csort(
    int2* __restrict__ stg, const int* __restrict__ boffs,
    int* __restrict__ offs) {
    __shared__ int2 buf[SORT_CAP];   // 32 KB
    __shared__ int  hist[NPB];       // 1 KB
    __shared__ int  cur[NPB];        // 1 KB
    __shared__ int  sdata[256];
    int b = blockIdx.x, t = threadIdx.x;
    int beg = boffs[b], end = boffs[b + 1], cnt = end - beg;

    for (int n = t; n < NPB; n += 256) hist[n] = 0;
    __syncthreads();

    int nlds = cnt < SORT_CAP ? cnt : SORT_CAP;
    for (int i = t; i < nlds; i += 256) {
        int2 p = stg[beg + i];
        buf[i] = p;
        atomicAdd(&hist[(p.x >> 17) & (NPB - 1)], 1);
    }
    // overflow remainder (statistically never: cap = mean + ~16 sigma) held in regs
    int2 r0{0,0}, r1{0,0}; int nr = 0;
    {
        int i0 = nlds + t, i1 = nlds + 256 + t;
        if (i0 < cnt) { r0 = stg[beg + i0]; atomicAdd(&hist[(r0.x >> 17) & (NPB - 1)], 1); nr = 1; }
        if (i1 < cnt) { r1 = stg[beg + i1]; atomicAdd(&hist[(r1.x >> 17) & (NPB - 1)], 1); nr = 2; }
    }
    __syncthreads();

    // exclusive scan of NPB(=256) counts, one per thread
    int c = hist[t];
    sdata[t] = c; __syncthreads();
    for (int off = 1; off < 256; off <<= 1) {
        int v = (t >= off) ? sdata[t - off] : 0;
        __syncthreads();
        if (t >= off) sdata[t] += v;
        __syncthreads();
    }
    int excl = (t == 0) ? 0 : sdata[t - 1];
    cur[t] = excl;
    int node = (b << BSH) + t;
    if (node < N_NODES) offs[node] = beg + excl;
    if (b == KB - 1 && t == 255) offs[N_NODES] = end;   // == E
    __syncthreads();

    // scatter LDS copy back to globally-sorted positions (in-place over [beg,end))
    for (int i = t; i < nlds; i += 256) {
        int2 p = buf[i];
        int pos = atomicAdd(&cur[(p.x >> 17) & (NPB - 1)], 1);
        stg[beg + pos] = p;
    }
    if (nr >= 1) { int pos = atomicAdd(&cur[(r0.x >> 17) & (NPB - 1)], 1); stg[beg + pos] = r0; }
    if (nr >= 2) { int pos = atomicAdd(&cur[(r1.x >> 17) & (NPB - 1)], 1); stg[beg + pos] = r1; }
}

// ---- gather: one wave per dst node, register accumulate, 4-deep unroll ----
__global__ __launch_bounds__(256) void k_gather(
    const float* __restrict__ x, const int* __restrict__ offs,
    const int2* __restrict__ stg, float* __restrict__ out) {
    int node = blockIdx.x * 4 + (threadIdx.x >> 6);
    int lane = threadIdx.x & 63;
    if (node >= N_NODES) return;
    int beg = offs[node], end = offs[node + 1];
    float a0 = 0.f, a1 = 0.f, a2 = 0.f, a3 = 0.f;
    int j = beg;
    for (; j + 3 < end; j += 4) {
        int2 p0 = stg[j];
        int2 p1 = stg[j + 1];
        int2 p2 = stg[j + 2];
        int2 p3 = stg[j + 3];
        a0 += __int_as_float(p0.y) * x[(size_t)(p0.x & 0x1FFFF) * N_FEAT + lane];
        a1 += __int_as_float(p1.y) * x[(size_t)(p1.x & 0x1FFFF) * N_FEAT + lane];
        a2 += __int_as_float(p2.y) * x[(size_t)(p2.x & 0x1FFFF) * N_FEAT + lane];
        a3 += __int_as_float(p3.y) * x[(size_t)(p3.x & 0x1FFFF) * N_FEAT + lane];
    }
    for (; j < end; ++j) {
        int2 p = stg[j];
        a0 += __int_as_float(p.y) * x[(size_t)(p.x & 0x1FFFF) * N_FEAT + lane];
    }
    out[(size_t)node * N_FEAT + lane] = (a0 + a1) + (a2 + a3);
}

// ---- fallback (R1 atomic scatter) ----
__global__ __launch_bounds__(256) void gnn_scatter_kernel(
    const float* __restrict__ x, const int* __restrict__ ei,
    const float* __restrict__ w, float* __restrict__ out, int E) {
    int e = blockIdx.x * 4 + (threadIdx.x >> 6);
    int lane = threadIdx.x & 63;
    if (e >= E) return;
    float v = w[e] * x[(size_t)ei[e] * N_FEAT + lane];
    atomicAdd(&out[(size_t)ei[E + e] * N_FEAT + lane], v);
}

static inline size_t align16(size_t v) { return (v + 15) & ~(size_t)15; }

extern "C" void kernel_launch(void* const* d_in, const int* in_sizes, int n_in,
                              void* d_out, int out_size, void* d_ws, size_t ws_size,
                              hipStream_t stream) {
    const float* x   = (const float*)d_in[0];
    const int*   ei  = (const int*)d_in[1];
    const float* w   = (const float*)d_in[2];
    float*       out = (float*)d_out;
    const int E = in_sizes[2];

    size_t off_bcur  = 0;
    size_t off_boffs = align16(off_bcur + (size_t)KB * 4);
    size_t off_offs  = align16(off_boffs + (size_t)(KB + 1) * 4);
    size_t off_stg   = align16(off_offs + (size_t)(N_NODES + 1) * 4);
    size_t need      = off_stg + (size_t)E * 8;

    if (ws_size < need) {
        hipMemsetAsync(d_out, 0, (size_t)out_size * sizeof(float), stream);
        gnn_scatter_kernel<<<(E + 3) / 4, 256, 0, stream>>>(x, ei, w, out, E);
        return;
    }

    char* ws    = (char*)d_ws;
    int*  bcur  = (int*)(ws + off_bcur);
    int*  boffs = (int*)(ws + off_boffs);
    int*  offs  = (int*)(ws + off_offs);
    int2* stg   = (int2*)(ws + off_stg);

    const int nblk = (E + FCHUNK - 1) / FCHUNK;   // 153

    hipMemsetAsync(bcur, 0, (size_t)KB * 4, stream);
    k_chist<<<nblk, 256, 0, stream>>>(ei, bcur, E);
    k_cscan<<<1, 256, 0, stream>>>(bcur, boffs);
    k_cbin<<<nblk, 256, 0, stream>>>(ei, w, bcur, stg, E);
    k_csort<<<KB, 256, 0, stream>>>(stg, boffs, offs);
    k_gather<<<(N_NODES + 3) / 4, 256, 0, stream>>>(x, offs, stg, out);
}

// Round 5
// 158.702 us; speedup vs baseline: 3.7097x; 1.2624x over previous
//
#include <hip/hip_runtime.h>
#include <hip/hip_bf16.h>

// LightGCNConv: out[dst] = sum_e w[e] * x[src_e], N=100000, d=64, E=1250000.
//
// R1: 80M fp32 device atomics -> 275us (atomic-rate bound, WRITE 320MB).
// R2: exact CSR, k_fill 8x write amp (90us) + k_gather 88us -> 295us.
// R3: fused LDS-accumulator gather, 1563 blocks -> 471us (latency-starved). REVERTED.
// R4: L2-resident CSR build + gather -> 200us. Gather 67us (FETCH 143MB =
//     ~5x re-fetch of x past L2); prep chain 133us (6 dispatches, 2 full ei
//     passes, 153-block kernels <1 blk/CU).
// R5: (a) x cast to bf16 (threshold 0.26 is bf16-floor; adds ~0.03 error) ->
//         halves gather row traffic AND working set (12.8MB);
//     (b) fixed-cap buckets (782 x cap2048 = mean+11sigma) kill hist+scan;
//         exact-correct overflow path (normally 0 entries);
//     (c) bin at 1024 thr/block for latency hiding;
//     (d) gather: 2 nodes/wave, ushort2 lanes -> 256B/instr, 4 FMA chains.
//     Fallback chain: A (26.7MB ws) -> B (R4 exact, 10.5MB, proven) -> C (R1).

#define N_NODES   100000
#define N_FEAT    64

// ---------------- Path A ----------------
#define A_BSH     7
#define A_NPB     (1 << A_BSH)                       // 128 nodes/bucket
#define A_KB      ((N_NODES + A_NPB - 1) >> A_BSH)   // 782 buckets
#define A_CAP     2048                               // slots/bucket (mean 1598)
#define A_FCHUNK  8192                               // edges per bin block
#define A_OVCAP   65536

__global__ __launch_bounds__(256) void k_cast(
    const float* __restrict__ x, ushort* __restrict__ xb) {
    int i = (blockIdx.x * 256 + threadIdx.x) * 4;
    if (i >= N_NODES * N_FEAT) return;
    float4 v = *(const float4*)(x + i);
    uint4 u = *(uint4*)&v;
    ushort4 r;
    r.x = (ushort)((u.x + 0x7FFFu + ((u.x >> 16) & 1)) >> 16);
    r.y = (ushort)((u.y + 0x7FFFu + ((u.y >> 16) & 1)) >> 16);
    r.z = (ushort)((u.z + 0x7FFFu + ((u.z >> 16) & 1)) >> 16);
    r.w = (ushort)((u.w + 0x7FFFu + ((u.w >> 16) & 1)) >> 16);
    *(ushort4*)(xb + i) = r;
}

// bin into fixed-cap buckets; 1024 threads/block; block-reserved runs
__global__ __launch_bounds__(1024) void k_bin(
    const int* __restrict__ ei, const float* __restrict__ w,
    int* __restrict__ bcur, int2* __restrict__ stg,
    int* __restrict__ ovf, int* __restrict__ ovcnt, int E) {
    __shared__ int h[A_KB];
    int t = threadIdx.x;
    for (int b = t; b < A_KB; b += 1024) h[b] = 0;
    __syncthreads();
    int e0 = blockIdx.x * A_FCHUNK;
    #pragma unroll
    for (int k = 0; k < A_FCHUNK / 1024; ++k) {
        int e = e0 + k * 1024 + t;
        if (e < E) atomicAdd(&h[ei[E + e] >> A_BSH], 1);
    }
    __syncthreads();
    for (int b = t; b < A_KB; b += 1024) {
        int c = h[b];
        h[b] = c ? atomicAdd(&bcur[b], c) : 0;   // bucket-local base
    }
    __syncthreads();
    #pragma unroll
    for (int k = 0; k < A_FCHUNK / 1024; ++k) {
        int e = e0 + k * 1024 + t;
        if (e < E) {
            int dst = ei[E + e];
            int b = dst >> A_BSH;
            int loc = atomicAdd(&h[b], 1);       // LDS int atomic
            if (loc < A_CAP) {
                stg[b * A_CAP + loc] =
                    make_int2(ei[e] | ((dst & (A_NPB - 1)) << 17),
                              __float_as_int(w[e]));
            } else {
                int oi = atomicAdd(ovcnt, 1);
                if (oi < A_OVCAP) ovf[oi] = e;
            }
        }
    }
}

// per-bucket LDS counting sort -> per-node [beg,end) into padded stg
__global__ __launch_bounds__(256) void k_sort(
    int2* __restrict__ stg, const int* __restrict__ bcur,
    int* __restrict__ beg, int* __restrict__ endp) {
    __shared__ int2 buf[A_CAP];      // 16 KB
    __shared__ int  hist[A_NPB];
    __shared__ int  cur[A_NPB];
    __shared__ int  sdata[256];
    int b = blockIdx.x, t = threadIdx.x;
    int cnt = bcur[b];
    if (cnt > A_CAP) cnt = A_CAP;
    int base = b * A_CAP;

    if (t < A_NPB) hist[t] = 0;
    __syncthreads();
    for (int i = t; i < cnt; i += 256) {
        int2 p = stg[base + i];
        buf[i] = p;
        atomicAdd(&hist[(p.x >> 17) & (A_NPB - 1)], 1);
    }
    __syncthreads();
    int c = (t < A_NPB) ? hist[t] : 0;
    sdata[t] = c; __syncthreads();
    for (int off = 1; off < 256; off <<= 1) {
        int v = (t >= off) ? sdata[t - off] : 0;
        __syncthreads();
        if (t >= off) sdata[t] += v;
        __syncthreads();
    }
    int excl = (t == 0) ? 0 : sdata[t - 1];
    if (t < A_NPB) {
        cur[t] = excl;
        int node = (b << A_BSH) + t;
        if (node < N_NODES) { beg[node] = base + excl; endp[node] = base + excl + c; }
    }
    __syncthreads();
    for (int i = t; i < cnt; i += 256) {
        int2 p = buf[i];
        int pos = atomicAdd(&cur[(p.x >> 17) & (A_NPB - 1)], 1);
        stg[base + pos] = p;
    }
}

// gather: 2 nodes per wave (half-wave each), bf16 x rows via ushort2 lanes
__global__ __launch_bounds__(256) void k_gather2(
    const ushort* __restrict__ xb, const int* __restrict__ beg,
    const int* __restrict__ endp, const int2* __restrict__ stg,
    float* __restrict__ out) {
    int wid  = threadIdx.x >> 6;
    int lane = threadIdx.x & 63;
    int half = lane >> 5;                  // 0/1: which node in the wave
    int l    = lane & 31;                  // ushort2 column
    int node = blockIdx.x * 8 + wid * 2 + half;
    if (node >= N_NODES) return;
    int j = beg[node], end = endp[node];
    const ushort2* xb2 = (const ushort2*)xb;
    float a0x = 0.f, a0y = 0.f, a1x = 0.f, a1y = 0.f;
    for (; j + 3 < end; j += 4) {
        int2 p0 = stg[j];
        int2 p1 = stg[j + 1];
        int2 p2 = stg[j + 2];
        int2 p3 = stg[j + 3];
        ushort2 u0 = xb2[(size_t)(p0.x & 0x1FFFF) * 32 + l];
        ushort2 u1 = xb2[(size_t)(p1.x & 0x1FFFF) * 32 + l];
        ushort2 u2 = xb2[(size_t)(p2.x & 0x1FFFF) * 32 + l];
        ushort2 u3 = xb2[(size_t)(p3.x & 0x1FFFF) * 32 + l];
        float w0 = __int_as_float(p0.y), w1 = __int_as_float(p1.y);
        float w2 = __int_as_float(p2.y), w3 = __int_as_float(p3.y);
        a0x += w0 * __uint_as_float((uint)u0.x << 16);
        a0y += w0 * __uint_as_float((uint)u0.y << 16);
        a1x += w1 * __uint_as_float((uint)u1.x << 16);
        a1y += w1 * __uint_as_float((uint)u1.y << 16);
        a0x += w2 * __uint_as_float((uint)u2.x << 16);
        a0y += w2 * __uint_as_float((uint)u2.y << 16);
        a1x += w3 * __uint_as_float((uint)u3.x << 16);
        a1y += w3 * __uint_as_float((uint)u3.y << 16);
    }
    for (; j < end; ++j) {
        int2 p = stg[j];
        ushort2 u = xb2[(size_t)(p.x & 0x1FFFF) * 32 + l];
        float wv = __int_as_float(p.y);
        a0x += wv * __uint_as_float((uint)u.x << 16);
        a0y += wv * __uint_as_float((uint)u.y << 16);
    }
    float2 r; r.x = a0x + a1x; r.y = a0y + a1y;
    ((float2*)out)[(size_t)node * 32 + l] = r;
}

// overflow fix-up (normally 0 entries): exact fp32 atomic adds
__global__ __launch_bounds__(256) void k_ovf(
    const float* __restrict__ x, const int* __restrict__ ei,
    const float* __restrict__ w, const int* __restrict__ ovf,
    const int* __restrict__ ovcnt, float* __restrict__ out, int E) {
    int n = *ovcnt;
    if (n > A_OVCAP) n = A_OVCAP;
    int wid  = blockIdx.x * 4 + (threadIdx.x >> 6);
    int lane = threadIdx.x & 63;
    for (int i = wid; i < n; i += gridDim.x * 4) {
        int e = ovf[i];
        float v = w[e] * x[(size_t)ei[e] * N_FEAT + lane];
        atomicAdd(&out[(size_t)ei[E + e] * N_FEAT + lane], v);
    }
}

// ---------------- Path B (R4 exact pipeline, proven 200us) ----------------
#define BSH       8
#define NPB       (1 << BSH)
#define KB        ((N_NODES + NPB - 1) >> BSH)     // 391
#define FCHUNK    8192
#define SORT_CAP  4096

__global__ __launch_bounds__(256) void k_chist(
    const int* __restrict__ ei, int* __restrict__ bcur, int E) {
    __shared__ int h[KB];
    int t = threadIdx.x;
    for (int b = t; b < KB; b += 256) h[b] = 0;
    __syncthreads();
    int e0 = blockIdx.x * FCHUNK;
    #pragma unroll
    for (int k = 0; k < FCHUNK / 256; ++k) {
        int e = e0 + k * 256 + t;
        if (e < E) atomicAdd(&h[ei[E + e] >> BSH], 1);
    }
    __syncthreads();
    for (int b = t; b < KB; b += 256) if (h[b]) atomicAdd(&bcur[b], h[b]);
}

__global__ __launch_bounds__(256) void k_cscan(
    int* __restrict__ bcur, int* __restrict__ boffs) {
    __shared__ int sdata[256];
    int t = threadIdx.x;
    int i0 = 2 * t, i1 = 2 * t + 1;
    int v0 = (i0 < KB) ? bcur[i0] : 0;
    int v1 = (i1 < KB) ? bcur[i1] : 0;
    sdata[t] = v0 + v1; __syncthreads();
    for (int off = 1; off < 256; off <<= 1) {
        int v = (t >= off) ? sdata[t - off] : 0;
        __syncthreads();
        if (t >= off) sdata[t] += v;
        __syncthreads();
    }
    int run = (t == 0) ? 0 : sdata[t - 1];
    if (i0 < KB) { boffs[i0] = run; bcur[i0] = run; }
    run += v0;
    if (i1 < KB) { boffs[i1] = run; bcur[i1] = run; }
    if (t == 255) boffs[KB] = sdata[255];
}

__global__ __launch_bounds__(256) void k_cbin(
    const int* __restrict__ ei, const float* __restrict__ w,
    int* __restrict__ bcur, int2* __restrict__ stg, int E) {
    __shared__ int h[KB];
    int t = threadIdx.x;
    for (int b = t; b < KB; b += 256) h[b] = 0;
    __syncthreads();
    int e0 = blockIdx.x * FCHUNK;
    #pragma unroll
    for (int k = 0; k < FCHUNK / 256; ++k) {
        int e = e0 + k * 256 + t;
        if (e < E) atomicAdd(&h[ei[E + e] >> BSH], 1);
    }
    __syncthreads();
    for (int b = t; b < KB; b += 256) {
        int c = h[b];
        h[b] = c ? atomicAdd(&bcur[b], c) : 0;
    }
    __syncthreads();
    #pragma unroll
    for (int k = 0; k < FCHUNK / 256; ++k) {
        int e = e0 + k * 256 + t;
        if (e < E) {
            int dst = ei[E + e];
            int slot = atomicAdd(&h[dst >> BSH], 1);
            stg[slot] = make_int2(ei[e] | ((dst & (NPB - 1)) << 17),
                                  __float_as_int(w[e]));
        }
    }
}

__global__ __launch_bounds__(256) void k_csort(
    int2* __restrict__ stg, const int* __restrict__ boffs,
    int* __restrict__ offs) {
    __shared__ int2 buf[SORT_CAP];
    __shared__ int  hist[NPB];
    __shared__ int  cur[NPB];
    __shared__ int  sdata[256];
    int b = blockIdx.x, t = threadIdx.x;
    int bg = boffs[b], end = boffs[b + 1], cnt = end - bg;
    for (int n = t; n < NPB; n += 256) hist[n] = 0;
    __syncthreads();
    int nlds = cnt < SORT_CAP ? cnt : SORT_CAP;
    for (int i = t; i < nlds; i += 256) {
        int2 p = stg[bg + i];
        buf[i] = p;
        atomicAdd(&hist[(p.x >> 17) & (NPB - 1)], 1);
    }
    int2 r0{0,0}, r1{0,0}; int nr = 0;
    {
        int i0 = nlds + t, i1 = nlds + 256 + t;
        if (i0 < cnt) { r0 = stg[bg + i0]; atomicAdd(&hist[(r0.x >> 17) & (NPB - 1)], 1); nr = 1; }
        if (i1 < cnt) { r1 = stg[bg + i1]; atomicAdd(&hist[(r1.x >> 17) & (NPB - 1)], 1); nr = 2; }
    }
    __syncthreads();
    int c = hist[t];
    sdata[t] = c; __syncthreads();
    for (int off = 1; off < 256; off <<= 1) {
        int v = (t >= off) ? sdata[t - off] : 0;
        __syncthreads();
        if (t >= off) sdata[t] += v;
        __syncthreads();
    }
    int excl = (t == 0) ? 0 : sdata[t - 1];
    cur[t] = excl;
    int node = (b << BSH) + t;
    if (node < N_NODES) offs[node] = bg + excl;
    if (b == KB - 1 && t == 255) offs[N_NODES] = end;
    __syncthreads();
    for (int i = t; i < nlds; i += 256) {
        int2 p = buf[i];
        int pos = atomicAdd(&cur[(p.x >> 17) & (NPB - 1)], 1);
        stg[bg + pos] = p;
    }
    if (nr >= 1) { int pos = atomicAdd(&cur[(r0.x >> 17) & (NPB - 1)], 1); stg[bg + pos] = r0; }
    if (nr >= 2) { int pos = atomicAdd(&cur[(r1.x >> 17) & (NPB - 1)], 1); stg[bg + pos] = r1; }
}

__global__ __launch_bounds__(256) void k_gather(
    const float* __restrict__ x, const int* __restrict__ offs,
    const int2* __restrict__ stg, float* __restrict__ out) {
    int node = blockIdx.x * 4 + (threadIdx.x >> 6);
    int lane = threadIdx.x & 63;
    if (node >= N_NODES) return;
    int bg = offs[node], end = offs[node + 1];
    float a0 = 0.f, a1 = 0.f, a2 = 0.f, a3 = 0.f;
    int j = bg;
    for (; j + 3 < end; j += 4) {
        int2 p0 = stg[j];
        int2 p1 = stg[j + 1];
        int2 p2 = stg[j + 2];
        int2 p3 = stg[j + 3];
        a0 += __int_as_float(p0.y) * x[(size_t)(p0.x & 0x1FFFF) * N_FEAT + lane];
        a1 += __int_as_float(p1.y) * x[(size_t)(p1.x & 0x1FFFF) * N_FEAT + lane];
        a2 += __int_as_float(p2.y) * x[(size_t)(p2.x & 0x1FFFF) * N_FEAT + lane];
        a3 += __int_as_float(p3.y) * x[(size_t)(p3.x & 0x1FFFF) * N_FEAT + lane];
    }
    for (; j < end; ++j) {
        int2 p = stg[j];
        a0 += __int_as_float(p.y) * x[(size_t)(p.x & 0x1FFFF) * N_FEAT + lane];
    }
    out[(size_t)node * N_FEAT + lane] = (a0 + a1) + (a2 + a3);
}

// ---------------- Path C (R1 scatter) ----------------
__global__ __launch_bounds__(256) void gnn_scatter_kernel(
    const float* __restrict__ x, const int* __restrict__ ei,
    const float* __restrict__ w, float* __restrict__ out, int E) {
    int e = blockIdx.x * 4 + (threadIdx.x >> 6);
    int lane = threadIdx.x & 63;
    if (e >= E) return;
    float v = w[e] * x[(size_t)ei[e] * N_FEAT + lane];
    atomicAdd(&out[(size_t)ei[E + e] * N_FEAT + lane], v);
}

static inline size_t align16(size_t v) { return (v + 15) & ~(size_t)15; }

extern "C" void kernel_launch(void* const* d_in, const int* in_sizes, int n_in,
                              void* d_out, int out_size, void* d_ws, size_t ws_size,
                              hipStream_t stream) {
    const float* x   = (const float*)d_in[0];
    const int*   ei  = (const int*)d_in[1];
    const float* w   = (const float*)d_in[2];
    float*       out = (float*)d_out;
    const int E = in_sizes[2];
    char* ws = (char*)d_ws;

    // ---- Path A layout ----
    size_t a_xb   = 0;
    size_t a_stg  = align16(a_xb + (size_t)N_NODES * N_FEAT * 2);
    size_t a_beg  = align16(a_stg + (size_t)A_KB * A_CAP * 8);
    size_t a_end  = align16(a_beg + (size_t)N_NODES * 4);
    size_t a_bcur = align16(a_end + (size_t)N_NODES * 4);     // KB ints + ovcnt
    size_t a_ovf  = align16(a_bcur + (size_t)(A_KB + 1) * 4);
    size_t need_a = a_ovf + (size_t)A_OVCAP * 4;

    if (ws_size >= need_a) {
        ushort* xb   = (ushort*)(ws + a_xb);
        int2*   stg  = (int2*)(ws + a_stg);
        int*    beg  = (int*)(ws + a_beg);
        int*    endp = (int*)(ws + a_end);
        int*    bcur = (int*)(ws + a_bcur);
        int*    ovcnt = bcur + A_KB;
        int*    ovf  = (int*)(ws + a_ovf);

        hipMemsetAsync(bcur, 0, (size_t)(A_KB + 1) * 4, stream);
        k_cast<<<(N_NODES * N_FEAT / 4 + 255) / 256, 256, 0, stream>>>(x, xb);
        k_bin<<<(E + A_FCHUNK - 1) / A_FCHUNK, 1024, 0, stream>>>(
            ei, w, bcur, stg, ovf, ovcnt, E);
        k_sort<<<A_KB, 256, 0, stream>>>(stg, bcur, beg, endp);
        k_gather2<<<(N_NODES + 7) / 8, 256, 0, stream>>>(xb, beg, endp, stg, out);
        k_ovf<<<16, 256, 0, stream>>>(x, ei, w, ovf, ovcnt, out, E);
        return;
    }

    // ---- Path B layout (R4) ----
    size_t b_bcur  = 0;
    size_t b_boffs = align16(b_bcur + (size_t)KB * 4);
    size_t b_offs  = align16(b_boffs + (size_t)(KB + 1) * 4);
    size_t b_stg   = align16(b_offs + (size_t)(N_NODES + 1) * 4);
    size_t need_b  = b_stg + (size_t)E * 8;

    if (ws_size >= need_b) {
        int*  bcur  = (int*)(ws + b_bcur);
        int*  boffs = (int*)(ws + b_boffs);
        int*  offs  = (int*)(ws + b_offs);
        int2* stg   = (int2*)(ws + b_stg);
        const int nblk = (E + FCHUNK - 1) / FCHUNK;
        hipMemsetAsync(bcur, 0, (size_t)KB * 4, stream);
        k_chist<<<nblk, 256, 0, stream>>>(ei, bcur, E);
        k_cscan<<<1, 256, 0, stream>>>(bcur, boffs);
        k_cbin<<<nblk, 256, 0, stream>>>(ei, w, bcur, stg, E);
        k_csort<<<KB, 256, 0, stream>>>(stg, boffs, offs);
        k_gather<<<(N_NODES + 3) / 4, 256, 0, stream>>>(x, offs, stg, out);
        return;
    }

    // ---- Path C ----
    hipMemsetAsync(d_out, 0, (size_t)out_size * sizeof(float), stream);
    gnn_scatter_kernel<<<(E + 3) / 4, 256, 0, stream>>>(x, ei, w, out, E);
}

// Round 6
// 158.376 us; speedup vs baseline: 3.7173x; 1.0021x over previous
//
#include <hip/hip_runtime.h>
#include <hip/hip_bf16.h>

// LightGCNConv: out[dst] = sum_e w[e] * x[src_e], N=100000, d=64, E=1250000.
//
// R1: 80M fp32 device atomics -> 275us kernel (atomic-rate bound).
// R2: exact CSR; fill 8x write amp 90us + gather 88us -> 295 total.
// R3: fused LDS-accumulator gather (1563 blocks) -> 471us, latency-starved. REVERTED.
// R4: L2-resident CSR build + reg-accumulate gather -> 200 total (gather 67).
// R5: bf16 x (halves gather traffic), fixed-cap buckets (no hist/scan),
//     2 nodes/wave gather -> 158.7 total, absmax 0.0625 (thr 0.26).
//     PROFILE INSIGHT: top-5 dispatches are harness 0xAA poison fills of the
//     256MiB d_ws (43us each) -> dur_us carries ~65-70us fixed harness
//     overhead. Controllable pipeline ~89us: cast 8, bin 28, sort 12,
//     gather 35, glue 6.
// R6: (a) fuse cast+bin into one dispatch (block-role split; cast hides
//         behind bin's LDS work);
//     (b) gather 4 nodes/wave: quarter-wave x ushort4 = 128B row, 4x edge
//         streams/wave, float4 output stores (R4 gather was issue-limited:
//         VALUBusy 24% @ 12 VGPRs).
//     Fallback chain: A (26.7MB ws) -> B (R4 exact, 10.5MB) -> C (R1).

#define N_NODES   100000
#define N_FEAT    64

// ---------------- Path A ----------------
#define A_BSH     7
#define A_NPB     (1 << A_BSH)                       // 128 nodes/bucket
#define A_KB      ((N_NODES + A_NPB - 1) >> A_BSH)   // 782 buckets
#define A_CAP     2048                               // slots/bucket (mean 1598)
#define A_FCHUNK  8192                               // edges per bin block
#define A_OVCAP   65536
#define NBIN      ((1250000 + A_FCHUNK - 1) / A_FCHUNK)   // 153 (E known)
#define NCAST     391   // 391*1024*4 float4 = 1.6016M >= 1.6M

// fused: blocks [0,NBIN) bin edges; blocks [NBIN,NBIN+NCAST) cast x->bf16
__global__ __launch_bounds__(1024) void k_castbin(
    const float* __restrict__ x, ushort* __restrict__ xb,
    const int* __restrict__ ei, const float* __restrict__ w,
    int* __restrict__ bcur, int2* __restrict__ stg,
    int* __restrict__ ovf, int* __restrict__ ovcnt, int E) {
    int t = threadIdx.x;
    if (blockIdx.x >= NBIN) {
        // ---- cast role ----
        int cb = blockIdx.x - NBIN;
        #pragma unroll
        for (int k = 0; k < 4; ++k) {
            int i4 = cb * 4096 + k * 1024 + t;           // float4 index
            if (i4 < N_NODES * N_FEAT / 4) {
                float4 v = ((const float4*)x)[i4];
                uint4 u = *(uint4*)&v;
                ushort4 r;
                r.x = (ushort)((u.x + 0x7FFFu + ((u.x >> 16) & 1)) >> 16);
                r.y = (ushort)((u.y + 0x7FFFu + ((u.y >> 16) & 1)) >> 16);
                r.z = (ushort)((u.z + 0x7FFFu + ((u.z >> 16) & 1)) >> 16);
                r.w = (ushort)((u.w + 0x7FFFu + ((u.w >> 16) & 1)) >> 16);
                ((ushort4*)xb)[i4] = r;
            }
        }
        return;
    }
    // ---- bin role ----
    __shared__ int h[A_KB];
    for (int b = t; b < A_KB; b += 1024) h[b] = 0;
    __syncthreads();
    int e0 = blockIdx.x * A_FCHUNK;
    #pragma unroll
    for (int k = 0; k < A_FCHUNK / 1024; ++k) {
        int e = e0 + k * 1024 + t;
        if (e < E) atomicAdd(&h[ei[E + e] >> A_BSH], 1);
    }
    __syncthreads();
    for (int b = t; b < A_KB; b += 1024) {
        int c = h[b];
        h[b] = c ? atomicAdd(&bcur[b], c) : 0;   // bucket-local base
    }
    __syncthreads();
    #pragma unroll
    for (int k = 0; k < A_FCHUNK / 1024; ++k) {
        int e = e0 + k * 1024 + t;
        if (e < E) {
            int dst = ei[E + e];
            int b = dst >> A_BSH;
            int loc = atomicAdd(&h[b], 1);       // LDS int atomic
            if (loc < A_CAP) {
                stg[b * A_CAP + loc] =
                    make_int2(ei[e] | ((dst & (A_NPB - 1)) << 17),
                              __float_as_int(w[e]));
            } else {
                int oi = atomicAdd(ovcnt, 1);
                if (oi < A_OVCAP) ovf[oi] = e;
            }
        }
    }
}

// per-bucket LDS counting sort -> per-node [beg,end) into padded stg
__global__ __launch_bounds__(256) void k_sort(
    int2* __restrict__ stg, const int* __restrict__ bcur,
    int* __restrict__ beg, int* __restrict__ endp) {
    __shared__ int2 buf[A_CAP];      // 16 KB
    __shared__ int  hist[A_NPB];
    __shared__ int  cur[A_NPB];
    __shared__ int  sdata[256];
    int b = blockIdx.x, t = threadIdx.x;
    int cnt = bcur[b];
    if (cnt > A_CAP) cnt = A_CAP;
    int base = b * A_CAP;

    if (t < A_NPB) hist[t] = 0;
    __syncthreads();
    for (int i = t; i < cnt; i += 256) {
        int2 p = stg[base + i];
        buf[i] = p;
        atomicAdd(&hist[(p.x >> 17) & (A_NPB - 1)], 1);
    }
    __syncthreads();
    int c = (t < A_NPB) ? hist[t] : 0;
    sdata[t] = c; __syncthreads();
    for (int off = 1; off < 256; off <<= 1) {
        int v = (t >= off) ? sdata[t - off] : 0;
        __syncthreads();
        if (t >= off) sdata[t] += v;
        __syncthreads();
    }
    int excl = (t == 0) ? 0 : sdata[t - 1];
    if (t < A_NPB) {
        cur[t] = excl;
        int node = (b << A_BSH) + t;
        if (node < N_NODES) { beg[node] = base + excl; endp[node] = base + excl + c; }
    }
    __syncthreads();
    for (int i = t; i < cnt; i += 256) {
        int2 p = buf[i];
        int pos = atomicAdd(&cur[(p.x >> 17) & (A_NPB - 1)], 1);
        stg[base + pos] = p;
    }
}

// gather: 4 nodes/wave (quarter-wave each), bf16 rows via ushort4 (128B/row)
__global__ __launch_bounds__(256) void k_gather4(
    const ushort* __restrict__ xb, const int* __restrict__ beg,
    const int* __restrict__ endp, const int2* __restrict__ stg,
    float* __restrict__ out) {
    int wid  = threadIdx.x >> 6;
    int lane = threadIdx.x & 63;
    int q    = lane >> 4;                  // 0..3: node slot within wave
    int l    = lane & 15;                  // ushort4 column (16 x 8B = 128B)
    int node = blockIdx.x * 16 + wid * 4 + q;
    if (node >= N_NODES) return;
    int j = beg[node], end = endp[node];
    const ushort4* xb4 = (const ushort4*)xb;
    float ax0 = 0.f, ay0 = 0.f, az0 = 0.f, aw0 = 0.f;
    float ax1 = 0.f, ay1 = 0.f, az1 = 0.f, aw1 = 0.f;
    for (; j + 1 < end; j += 2) {
        int2 p0 = stg[j];
        int2 p1 = stg[j + 1];
        ushort4 u0 = xb4[(size_t)(p0.x & 0x1FFFF) * 16 + l];
        ushort4 u1 = xb4[(size_t)(p1.x & 0x1FFFF) * 16 + l];
        float w0 = __int_as_float(p0.y), w1 = __int_as_float(p1.y);
        ax0 += w0 * __uint_as_float((uint)u0.x << 16);
        ay0 += w0 * __uint_as_float((uint)u0.y << 16);
        az0 += w0 * __uint_as_float((uint)u0.z << 16);
        aw0 += w0 * __uint_as_float((uint)u0.w << 16);
        ax1 += w1 * __uint_as_float((uint)u1.x << 16);
        ay1 += w1 * __uint_as_float((uint)u1.y << 16);
        az1 += w1 * __uint_as_float((uint)u1.z << 16);
        aw1 += w1 * __uint_as_float((uint)u1.w << 16);
    }
    if (j < end) {
        int2 p = stg[j];
        ushort4 u = xb4[(size_t)(p.x & 0x1FFFF) * 16 + l];
        float wv = __int_as_float(p.y);
        ax0 += wv * __uint_as_float((uint)u.x << 16);
        ay0 += wv * __uint_as_float((uint)u.y << 16);
        az0 += wv * __uint_as_float((uint)u.z << 16);
        aw0 += wv * __uint_as_float((uint)u.w << 16);
    }
    float4 r;
    r.x = ax0 + ax1; r.y = ay0 + ay1; r.z = az0 + az1; r.w = aw0 + aw1;
    ((float4*)out)[(size_t)node * 16 + l] = r;
}

// overflow fix-up (normally 0 entries): exact fp32 atomic adds
__global__ __launch_bounds__(256) void k_ovf(
    const float* __restrict__ x, const int* __restrict__ ei,
    const float* __restrict__ w, const int* __restrict__ ovf,
    const int* __restrict__ ovcnt, float* __restrict__ out, int E) {
    int n = *ovcnt;
    if (n > A_OVCAP) n = A_OVCAP;
    int wid  = blockIdx.x * 4 + (threadIdx.x >> 6);
    int lane = threadIdx.x & 63;
    for (int i = wid; i < n; i += gridDim.x * 4) {
        int e = ovf[i];
        float v = w[e] * x[(size_t)ei[e] * N_FEAT + lane];
        atomicAdd(&out[(size_t)ei[E + e] * N_FEAT + lane], v);
    }
}

// ---------------- Path B (R4 exact pipeline, proven 200us) ----------------
#define BSH       8
#define NPB       (1 << BSH)
#define KB        ((N_NODES + NPB - 1) >> BSH)     // 391
#define FCHUNK    8192
#define SORT_CAP  4096

__global__ __launch_bounds__(256) void k_chist(
    const int* __restrict__ ei, int* __restrict__ bcur, int E) {
    __shared__ int h[KB];
    int t = threadIdx.x;
    for (int b = t; b < KB; b += 256) h[b] = 0;
    __syncthreads();
    int e0 = blockIdx.x * FCHUNK;
    #pragma unroll
    for (int k = 0; k < FCHUNK / 256; ++k) {
        int e = e0 + k * 256 + t;
        if (e < E) atomicAdd(&h[ei[E + e] >> BSH], 1);
    }
    __syncthreads();
    for (int b = t; b < KB; b += 256) if (h[b]) atomicAdd(&bcur[b], h[b]);
}

__global__ __launch_bounds__(256) void k_cscan(
    int* __restrict__ bcur, int* __restrict__ boffs) {
    __shared__ int sdata[256];
    int t = threadIdx.x;
    int i0 = 2 * t, i1 = 2 * t + 1;
    int v0 = (i0 < KB) ? bcur[i0] : 0;
    int v1 = (i1 < KB) ? bcur[i1] : 0;
    sdata[t] = v0 + v1; __syncthreads();
    for (int off = 1; off < 256; off <<= 1) {
        int v = (t >= off) ? sdata[t - off] : 0;
        __syncthreads();
        if (t >= off) sdata[t] += v;
        __syncthreads();
    }
    int run = (t == 0) ? 0 : sdata[t - 1];
    if (i0 < KB) { boffs[i0] = run; bcur[i0] = run; }
    run += v0;
    if (i1 < KB) { boffs[i1] = run; bcur[i1] = run; }
    if (t == 255) boffs[KB] = sdata[255];
}

__global__ __launch_bounds__(256) void k_cbin(
    const int* __restrict__ ei, const float* __restrict__ w,
    int* __restrict__ bcur, int2* __restrict__ stg, int E) {
    __shared__ int h[KB];
    int t = threadIdx.x;
    for (int b = t; b < KB; b += 256) h[b] = 0;
    __syncthreads();
    int e0 = blockIdx.x * FCHUNK;
    #pragma unroll
    for (int k = 0; k < FCHUNK / 256; ++k) {
        int e = e0 + k * 256 + t;
        if (e < E) atomicAdd(&h[ei[E + e] >> BSH], 1);
    }
    __syncthreads();
    for (int b = t; b < KB; b += 256) {
        int c = h[b];
        h[b] = c ? atomicAdd(&bcur[b], c) : 0;
    }
    __syncthreads();
    #pragma unroll
    for (int k = 0; k < FCHUNK / 256; ++k) {
        int e = e0 + k * 256 + t;
        if (e < E) {
            int dst = ei[E + e];
            int slot = atomicAdd(&h[dst >> BSH], 1);
            stg[slot] = make_int2(ei[e] | ((dst & (NPB - 1)) << 17),
                                  __float_as_int(w[e]));
        }
    }
}

__global__ __launch_bounds__(256) void k_csort(
    int2* __restrict__ stg, const int* __restrict__ boffs,
    int* __restrict__ offs) {
    __shared__ int2 buf[SORT_CAP];
    __shared__ int  hist[NPB];
    __shared__ int  cur[NPB];
    __shared__ int  sdata[256];
    int b = blockIdx.x, t = threadIdx.x;
    int bg = boffs[b], end = boffs[b + 1], cnt = end - bg;
    for (int n = t; n < NPB; n += 256) hist[n] = 0;
    __syncthreads();
    int nlds = cnt < SORT_CAP ? cnt : SORT_CAP;
    for (int i = t; i < nlds; i += 256) {
        int2 p = stg[bg + i];
        buf[i] = p;
        atomicAdd(&hist[(p.x >> 17) & (NPB - 1)], 1);
    }
    int2 r0{0,0}, r1{0,0}; int nr = 0;
    {
        int i0 = nlds + t, i1 = nlds + 256 + t;
        if (i0 < cnt) { r0 = stg[bg + i0]; atomicAdd(&hist[(r0.x >> 17) & (NPB - 1)], 1); nr = 1; }
        if (i1 < cnt) { r1 = stg[bg + i1]; atomicAdd(&hist[(r1.x >> 17) & (NPB - 1)], 1); nr = 2; }
    }
    __syncthreads();
    int c = hist[t];
    sdata[t] = c; __syncthreads();
    for (int off = 1; off < 256; off <<= 1) {
        int v = (t >= off) ? sdata[t - off] : 0;
        __syncthreads();
        if (t >= off) sdata[t] += v;
        __syncthreads();
    }
    int excl = (t == 0) ? 0 : sdata[t - 1];
    cur[t] = excl;
    int node = (b << BSH) + t;
    if (node < N_NODES) offs[node] = bg + excl;
    if (b == KB - 1 && t == 255) offs[N_NODES] = end;
    __syncthreads();
    for (int i = t; i < nlds; i += 256) {
        int2 p = buf[i];
        int pos = atomicAdd(&cur[(p.x >> 17) & (NPB - 1)], 1);
        stg[bg + pos] = p;
    }
    if (nr >= 1) { int pos = atomicAdd(&cur[(r0.x >> 17) & (NPB - 1)], 1); stg[bg + pos] = r0; }
    if (nr >= 2) { int pos = atomicAdd(&cur[(r1.x >> 17) & (NPB - 1)], 1); stg[bg + pos] = r1; }
}

__global__ __launch_bounds__(256) void k_gather(
    const float* __restrict__ x, const int* __restrict__ offs,
    const int2* __restrict__ stg, float* __restrict__ out) {
    int node = blockIdx.x * 4 + (threadIdx.x >> 6);
    int lane = threadIdx.x & 63;
    if (node >= N_NODES) return;
    int bg = offs[node], end = offs[node + 1];
    float a0 = 0.f, a1 = 0.f, a2 = 0.f, a3 = 0.f;
    int j = bg;
    for (; j + 3 < end; j += 4) {
        int2 p0 = stg[j];
        int2 p1 = stg[j + 1];
        int2 p2 = stg[j + 2];
        int2 p3 = stg[j + 3];
        a0 += __int_as_float(p0.y) * x[(size_t)(p0.x & 0x1FFFF) * N_FEAT + lane];
        a1 += __int_as_float(p1.y) * x[(size_t)(p1.x & 0x1FFFF) * N_FEAT + lane];
        a2 += __int_as_float(p2.y) * x[(size_t)(p2.x & 0x1FFFF) * N_FEAT + lane];
        a3 += __int_as_float(p3.y) * x[(size_t)(p3.x & 0x1FFFF) * N_FEAT + lane];
    }
    for (; j < end; ++j) {
        int2 p = stg[j];
        a0 += __int_as_float(p.y) * x[(size_t)(p.x & 0x1FFFF) * N_FEAT + lane];
    }
    out[(size_t)node * N_FEAT + lane] = (a0 + a1) + (a2 + a3);
}

// ---------------- Path C (R1 scatter) ----------------
__global__ __launch_bounds__(256) void gnn_scatter_kernel(
    const float* __restrict__ x, const int* __restrict__ ei,
    const float* __restrict__ w, float* __restrict__ out, int E) {
    int e = blockIdx.x * 4 + (threadIdx.x >> 6);
    int lane = threadIdx.x & 63;
    if (e >= E) return;
    float v = w[e] * x[(size_t)ei[e] * N_FEAT + lane];
    atomicAdd(&out[(size_t)ei[E + e] * N_FEAT + lane], v);
}

static inline size_t align16(size_t v) { return (v + 15) & ~(size_t)15; }

extern "C" void kernel_launch(void* const* d_in, const int* in_sizes, int n_in,
                              void* d_out, int out_size, void* d_ws, size_t ws_size,
                              hipStream_t stream) {
    const float* x   = (const float*)d_in[0];
    const int*   ei  = (const int*)d_in[1];
    const float* w   = (const float*)d_in[2];
    float*       out = (float*)d_out;
    const int E = in_sizes[2];
    char* ws = (char*)d_ws;

    // ---- Path A layout ----
    size_t a_xb   = 0;
    size_t a_stg  = align16(a_xb + (size_t)N_NODES * N_FEAT * 2);
    size_t a_beg  = align16(a_stg + (size_t)A_KB * A_CAP * 8);
    size_t a_end  = align16(a_beg + (size_t)N_NODES * 4);
    size_t a_bcur = align16(a_end + (size_t)N_NODES * 4);     // KB ints + ovcnt
    size_t a_ovf  = align16(a_bcur + (size_t)(A_KB + 1) * 4);
    size_t need_a = a_ovf + (size_t)A_OVCAP * 4;

    if (ws_size >= need_a && E == 1250000) {
        ushort* xb   = (ushort*)(ws + a_xb);
        int2*   stg  = (int2*)(ws + a_stg);
        int*    beg  = (int*)(ws + a_beg);
        int*    endp = (int*)(ws + a_end);
        int*    bcur = (int*)(ws + a_bcur);
        int*    ovcnt = bcur + A_KB;
        int*    ovf  = (int*)(ws + a_ovf);

        hipMemsetAsync(bcur, 0, (size_t)(A_KB + 1) * 4, stream);
        k_castbin<<<NBIN + NCAST, 1024, 0, stream>>>(
            x, xb, ei, w, bcur, stg, ovf, ovcnt, E);
        k_sort<<<A_KB, 256, 0, stream>>>(stg, bcur, beg, endp);
        k_gather4<<<(N_NODES + 15) / 16, 256, 0, stream>>>(xb, beg, endp, stg, out);
        k_ovf<<<16, 256, 0, stream>>>(x, ei, w, ovf, ovcnt, out, E);
        return;
    }

    // ---- Path B layout (R4) ----
    size_t b_bcur  = 0;
    size_t b_boffs = align16(b_bcur + (size_t)KB * 4);
    size_t b_offs  = align16(b_boffs + (size_t)(KB + 1) * 4);
    size_t b_stg   = align16(b_offs + (size_t)(N_NODES + 1) * 4);
    size_t need_b  = b_stg + (size_t)E * 8;

    if (ws_size >= need_b) {
        int*  bcur  = (int*)(ws + b_bcur);
        int*  boffs = (int*)(ws + b_boffs);
        int*  offs  = (int*)(ws + b_offs);
        int2* stg   = (int2*)(ws + b_stg);
        const int nblk = (E + FCHUNK - 1) / FCHUNK;
        hipMemsetAsync(bcur, 0, (size_t)KB * 4, stream);
        k_chist<<<nblk, 256, 0, stream>>>(ei, bcur, E);
        k_cscan<<<1, 256, 0, stream>>>(bcur, boffs);
        k_cbin<<<nblk, 256, 0, stream>>>(ei, w, bcur, stg, E);
        k_csort<<<KB, 256, 0, stream>>>(stg, boffs, offs);
        k_gather<<<(N_NODES + 3) / 4, 256, 0, stream>>>(x, offs, stg, out);
        return;
    }

    // ---- Path C ----
    hipMemsetAsync(d_out, 0, (size_t)out_size * sizeof(float), stream);
    gnn_scatter_kernel<<<(E + 3) / 4, 256, 0, stream>>>(x, ei, w, out, E);
}

// Round 7
// 135.600 us; speedup vs baseline: 4.3417x; 1.1680x over previous
//
#include <hip/hip_runtime.h>
#include <hip/hip_bf16.h>

// LightGCNConv: out[dst] = sum_e w[e] * x[src_e], N=100000, d=64, E=1250000.
//
// R1: 80M fp32 device atomics -> 275us kernel (atomics execute at fabric,
//     uncacheable: WRITE == E*256B == 320MB).
// R2: exact CSR; fill 8x write amp 90us + gather 88us -> 295 total.
// R3: per-bucket LDS-accumulate gather, 1563 blocks -> 471us. REVERTED.
// R4: L2-resident CSR build + reg-accumulate gather -> 200 total.
// R5: bf16 x + fixed-cap buckets (no hist/scan) -> 158.7. Harness poison of
//     256MiB d_ws + input restore = ~65us fixed overhead inside dur_us.
// R6: cast+bin fusion, 4-node/wave gather -> 158.4 (neutral; serial stages
//     + stg round-trips mask issue-rate gains).
// R7: fuse sort+gather per bucket: sorted payload stays in LDS (no writeback,
//     no re-read, no beg/end arrays, one fewer dispatch). 1024-thr blocks,
//     33.5KB LDS -> 2 blk/CU, 32 waves/CU. castbin: FCHUNK 4096, single
//     register-staged read of dst/src/w.
//     Fallback chain: A -> B (R4 exact, proven) -> C (R1).

#define N_NODES   100000
#define N_FEAT    64

// ---------------- Path A ----------------
#define A_BSH     7
#define A_NPB     (1 << A_BSH)                       // 128 nodes/bucket
#define A_KB      ((N_NODES + A_NPB - 1) >> A_BSH)   // 782 buckets
#define A_CAP     2048                               // slots/bucket (mean 1598)
#define A_FCHUNK  4096                               // edges per bin block
#define A_OVCAP   65536
#define NBIN      ((1250000 + A_FCHUNK - 1) / A_FCHUNK)   // 306 (E known)
#define NCAST     391   // 391*1024*4 float4 = 1.6016M >= 1.6M

// fused: blocks [0,NBIN) bin edges; blocks [NBIN,NBIN+NCAST) cast x->bf16
__global__ __launch_bounds__(1024) void k_castbin(
    const float* __restrict__ x, ushort* __restrict__ xb,
    const int* __restrict__ ei, const float* __restrict__ w,
    int* __restrict__ bcur, int2* __restrict__ stg,
    int* __restrict__ ovf, int* __restrict__ ovcnt, int E) {
    int t = threadIdx.x;
    if (blockIdx.x >= NBIN) {
        // ---- cast role ----
        int cb = blockIdx.x - NBIN;
        #pragma unroll
        for (int k = 0; k < 4; ++k) {
            int i4 = cb * 4096 + k * 1024 + t;           // float4 index
            if (i4 < N_NODES * N_FEAT / 4) {
                float4 v = ((const float4*)x)[i4];
                uint4 u = *(uint4*)&v;
                ushort4 r;
                r.x = (ushort)((u.x + 0x7FFFu + ((u.x >> 16) & 1)) >> 16);
                r.y = (ushort)((u.y + 0x7FFFu + ((u.y >> 16) & 1)) >> 16);
                r.z = (ushort)((u.z + 0x7FFFu + ((u.z >> 16) & 1)) >> 16);
                r.w = (ushort)((u.w + 0x7FFFu + ((u.w >> 16) & 1)) >> 16);
                ((ushort4*)xb)[i4] = r;
            }
        }
        return;
    }
    // ---- bin role: single register-staged read of dst/src/w ----
    __shared__ int h[A_KB];
    for (int b = t; b < A_KB; b += 1024) h[b] = 0;
    __syncthreads();
    int e0 = blockIdx.x * A_FCHUNK;
    int dstv[A_FCHUNK / 1024];
    int srcv[A_FCHUNK / 1024];
    float wv[A_FCHUNK / 1024];
    #pragma unroll
    for (int k = 0; k < A_FCHUNK / 1024; ++k) {
        int e = e0 + k * 1024 + t;
        bool ok = (e < E);
        dstv[k] = ok ? ei[E + e] : -1;
        srcv[k] = ok ? ei[e] : 0;
        wv[k]   = ok ? w[e] : 0.f;
        if (ok) atomicAdd(&h[dstv[k] >> A_BSH], 1);
    }
    __syncthreads();
    for (int b = t; b < A_KB; b += 1024) {
        int c = h[b];
        h[b] = c ? atomicAdd(&bcur[b], c) : 0;   // bucket-local base
    }
    __syncthreads();
    #pragma unroll
    for (int k = 0; k < A_FCHUNK / 1024; ++k) {
        if (dstv[k] >= 0) {
            int b = dstv[k] >> A_BSH;
            int loc = atomicAdd(&h[b], 1);       // LDS int atomic
            if (loc < A_CAP) {
                stg[b * A_CAP + loc] =
                    make_int2(srcv[k] | ((dstv[k] & (A_NPB - 1)) << 17),
                              __float_as_int(wv[k]));
            } else {
                int oi = atomicAdd(ovcnt, 1);
                if (oi < A_OVCAP) ovf[oi] = e0 + k * 1024 + t;
            }
        }
    }
}

// fused per-bucket counting sort (LDS-resident) + quarter-wave gather
__global__ __launch_bounds__(1024) void k_sortgather(
    const ushort* __restrict__ xb, const int* __restrict__ bcur,
    const int2* __restrict__ stg, float* __restrict__ out) {
    __shared__ int2 buf[A_CAP];      // 16 KB raw payload
    __shared__ int2 srt[A_CAP];      // 16 KB sorted payload
    __shared__ int  hist[A_NPB];     // per-node counts
    __shared__ int  start[A_NPB];    // per-node exclusive offsets
    __shared__ int  cur[A_NPB];      // scan temp / place cursor
    int b = blockIdx.x, t = threadIdx.x;
    int cnt = bcur[b];
    if (cnt > A_CAP) cnt = A_CAP;
    int base = b * A_CAP;

    if (t < A_NPB) hist[t] = 0;
    __syncthreads();
    for (int i = t; i < cnt; i += 1024) {
        int2 p = stg[base + i];
        buf[i] = p;
        atomicAdd(&hist[(p.x >> 17) & (A_NPB - 1)], 1);
    }
    __syncthreads();
    // Hillis-Steele inclusive scan of 128 counts (threads 0..127)
    if (t < A_NPB) cur[t] = hist[t];
    __syncthreads();
    for (int off = 1; off < A_NPB; off <<= 1) {
        int v = (t < A_NPB && t >= off) ? cur[t - off] : 0;
        __syncthreads();
        if (t < A_NPB && t >= off) cur[t] += v;
        __syncthreads();
    }
    if (t < A_NPB) start[t] = (t == 0) ? 0 : cur[t - 1];
    __syncthreads();
    if (t < A_NPB) cur[t] = start[t];
    __syncthreads();
    // place into sorted LDS buffer
    for (int i = t; i < cnt; i += 1024) {
        int2 p = buf[i];
        int pos = atomicAdd(&cur[(p.x >> 17) & (A_NPB - 1)], 1);
        srt[pos] = p;
    }
    __syncthreads();

    // gather: 16 waves x 4 quarter-slots = 64 nodes per pass, 2 passes
    int wid  = t >> 6;                 // 0..15
    int lane = t & 63;
    int q    = lane >> 4;              // quarter slot
    int l    = lane & 15;              // ushort4 column
    const ushort4* xb4 = (const ushort4*)xb;
    #pragma unroll
    for (int pass = 0; pass < 2; ++pass) {
        int n = pass * 64 + wid * 4 + q;           // local node 0..127
        int node = (b << A_BSH) + n;
        int j = start[n], end = start[n] + hist[n];
        float ax0 = 0.f, ay0 = 0.f, az0 = 0.f, aw0 = 0.f;
        float ax1 = 0.f, ay1 = 0.f, az1 = 0.f, aw1 = 0.f;
        for (; j + 1 < end; j += 2) {
            int2 p0 = srt[j];
            int2 p1 = srt[j + 1];
            ushort4 u0 = xb4[(size_t)(p0.x & 0x1FFFF) * 16 + l];
            ushort4 u1 = xb4[(size_t)(p1.x & 0x1FFFF) * 16 + l];
            float w0 = __int_as_float(p0.y), w1 = __int_as_float(p1.y);
            ax0 += w0 * __uint_as_float((uint)u0.x << 16);
            ay0 += w0 * __uint_as_float((uint)u0.y << 16);
            az0 += w0 * __uint_as_float((uint)u0.z << 16);
            aw0 += w0 * __uint_as_float((uint)u0.w << 16);
            ax1 += w1 * __uint_as_float((uint)u1.x << 16);
            ay1 += w1 * __uint_as_float((uint)u1.y << 16);
            az1 += w1 * __uint_as_float((uint)u1.z << 16);
            aw1 += w1 * __uint_as_float((uint)u1.w << 16);
        }
        if (j < end) {
            int2 p = srt[j];
            ushort4 u = xb4[(size_t)(p.x & 0x1FFFF) * 16 + l];
            float wv = __int_as_float(p.y);
            ax0 += wv * __uint_as_float((uint)u.x << 16);
            ay0 += wv * __uint_as_float((uint)u.y << 16);
            az0 += wv * __uint_as_float((uint)u.z << 16);
            aw0 += wv * __uint_as_float((uint)u.w << 16);
        }
        if (node < N_NODES) {
            float4 r;
            r.x = ax0 + ax1; r.y = ay0 + ay1;
            r.z = az0 + az1; r.w = aw0 + aw1;
            ((float4*)out)[(size_t)node * 16 + l] = r;
        }
    }
}

// overflow fix-up (normally 0 entries): exact fp32 atomic adds
__global__ __launch_bounds__(256) void k_ovf(
    const float* __restrict__ x, const int* __restrict__ ei,
    const float* __restrict__ w, const int* __restrict__ ovf,
    const int* __restrict__ ovcnt, float* __restrict__ out, int E) {
    int n = *ovcnt;
    if (n > A_OVCAP) n = A_OVCAP;
    int wid  = blockIdx.x * 4 + (threadIdx.x >> 6);
    int lane = threadIdx.x & 63;
    for (int i = wid; i < n; i += gridDim.x * 4) {
        int e = ovf[i];
        float v = w[e] * x[(size_t)ei[e] * N_FEAT + lane];
        atomicAdd(&out[(size_t)ei[E + e] * N_FEAT + lane], v);
    }
}

// ---------------- Path B (R4 exact pipeline, proven 200us) ----------------
#define BSH       8
#define NPB       (1 << BSH)
#define KB        ((N_NODES + NPB - 1) >> BSH)     // 391
#define FCHUNK    8192
#define SORT_CAP  4096

__global__ __launch_bounds__(256) void k_chist(
    const int* __restrict__ ei, int* __restrict__ bcur, int E) {
    __shared__ int h[KB];
    int t = threadIdx.x;
    for (int b = t; b < KB; b += 256) h[b] = 0;
    __syncthreads();
    int e0 = blockIdx.x * FCHUNK;
    #pragma unroll
    for (int k = 0; k < FCHUNK / 256; ++k) {
        int e = e0 + k * 256 + t;
        if (e < E) atomicAdd(&h[ei[E + e] >> BSH], 1);
    }
    __syncthreads();
    for (int b = t; b < KB; b += 256) if (h[b]) atomicAdd(&bcur[b], h[b]);
}

__global__ __launch_bounds__(256) void k_cscan(
    int* __restrict__ bcur, int* __restrict__ boffs) {
    __shared__ int sdata[256];
    int t = threadIdx.x;
    int i0 = 2 * t, i1 = 2 * t + 1;
    int v0 = (i0 < KB) ? bcur[i0] : 0;
    int v1 = (i1 < KB) ? bcur[i1] : 0;
    sdata[t] = v0 + v1; __syncthreads();
    for (int off = 1; off < 256; off <<= 1) {
        int v = (t >= off) ? sdata[t - off] : 0;
        __syncthreads();
        if (t >= off) sdata[t] += v;
        __syncthreads();
    }
    int run = (t == 0) ? 0 : sdata[t - 1];
    if (i0 < KB) { boffs[i0] = run; bcur[i0] = run; }
    run += v0;
    if (i1 < KB) { boffs[i1] = run; bcur[i1] = run; }
    if (t == 255) boffs[KB] = sdata[255];
}

__global__ __launch_bounds__(256) void k_cbin(
    const int* __restrict__ ei, const float* __restrict__ w,
    int* __restrict__ bcur, int2* __restrict__ stg, int E) {
    __shared__ int h[KB];
    int t = threadIdx.x;
    for (int b = t; b < KB; b += 256) h[b] = 0;
    __syncthreads();
    int e0 = blockIdx.x * FCHUNK;
    #pragma unroll
    for (int k = 0; k < FCHUNK / 256; ++k) {
        int e = e0 + k * 256 + t;
        if (e < E) atomicAdd(&h[ei[E + e] >> BSH], 1);
    }
    __syncthreads();
    for (int b = t; b < KB; b += 256) {
        int c = h[b];
        h[b] = c ? atomicAdd(&bcur[b], c) : 0;
    }
    __syncthreads();
    #pragma unroll
    for (int k = 0; k < FCHUNK / 256; ++k) {
        int e = e0 + k * 256 + t;
        if (e < E) {
            int dst = ei[E + e];
            int slot = atomicAdd(&h[dst >> BSH], 1);
            stg[slot] = make_int2(ei[e] | ((dst & (NPB - 1)) << 17),
                                  __float_as_int(w[e]));
        }
    }
}

__global__ __launch_bounds__(256) void k_csort(
    int2* __restrict__ stg, const int* __restrict__ boffs,
    int* __restrict__ offs) {
    __shared__ int2 buf[SORT_CAP];
    __shared__ int  hist[NPB];
    __shared__ int  cur[NPB];
    __shared__ int  sdata[256];
    int b = blockIdx.x, t = threadIdx.x;
    int bg = boffs[b], end = boffs[b + 1], cnt = end - bg;
    for (int n = t; n < NPB; n += 256) hist[n] = 0;
    __syncthreads();
    int nlds = cnt < SORT_CAP ? cnt : SORT_CAP;
    for (int i = t; i < nlds; i += 256) {
        int2 p = stg[bg + i];
        buf[i] = p;
        atomicAdd(&hist[(p.x >> 17) & (NPB - 1)], 1);
    }
    int2 r0{0,0}, r1{0,0}; int nr = 0;
    {
        int i0 = nlds + t, i1 = nlds + 256 + t;
        if (i0 < cnt) { r0 = stg[bg + i0]; atomicAdd(&hist[(r0.x >> 17) & (NPB - 1)], 1); nr = 1; }
        if (i1 < cnt) { r1 = stg[bg + i1]; atomicAdd(&hist[(r1.x >> 17) & (NPB - 1)], 1); nr = 2; }
    }
    __syncthreads();
    int c = hist[t];
    sdata[t] = c; __syncthreads();
    for (int off = 1; off < 256; off <<= 1) {
        int v = (t >= off) ? sdata[t - off] : 0;
        __syncthreads();
        if (t >= off) sdata[t] += v;
        __syncthreads();
    }
    int excl = (t == 0) ? 0 : sdata[t - 1];
    cur[t] = excl;
    int node = (b << BSH) + t;
    if (node < N_NODES) offs[node] = bg + excl;
    if (b == KB - 1 && t == 255) offs[N_NODES] = end;
    __syncthreads();
    for (int i = t; i < nlds; i += 256) {
        int2 p = buf[i];
        int pos = atomicAdd(&cur[(p.x >> 17) & (NPB - 1)], 1);
        stg[bg + pos] = p;
    }
    if (nr >= 1) { int pos = atomicAdd(&cur[(r0.x >> 17) & (NPB - 1)], 1); stg[bg + pos] = r0; }
    if (nr >= 2) { int pos = atomicAdd(&cur[(r1.x >> 17) & (NPB - 1)], 1); stg[bg + pos] = r1; }
}

__global__ __launch_bounds__(256) void k_gather(
    const float* __restrict__ x, const int* __restrict__ offs,
    const int2* __restrict__ stg, float* __restrict__ out) {
    int node = blockIdx.x * 4 + (threadIdx.x >> 6);
    int lane = threadIdx.x & 63;
    if (node >= N_NODES) return;
    int bg = offs[node], end = offs[node + 1];
    float a0 = 0.f, a1 = 0.f, a2 = 0.f, a3 = 0.f;
    int j = bg;
    for (; j + 3 < end; j += 4) {
        int2 p0 = stg[j];
        int2 p1 = stg[j + 1];
        int2 p2 = stg[j + 2];
        int2 p3 = stg[j + 3];
        a0 += __int_as_float(p0.y) * x[(size_t)(p0.x & 0x1FFFF) * N_FEAT + lane];
        a1 += __int_as_float(p1.y) * x[(size_t)(p1.x & 0x1FFFF) * N_FEAT + lane];
        a2 += __int_as_float(p2.y) * x[(size_t)(p2.x & 0x1FFFF) * N_FEAT + lane];
        a3 += __int_as_float(p3.y) * x[(size_t)(p3.x & 0x1FFFF) * N_FEAT + lane];
    }
    for (; j < end; ++j) {
        int2 p = stg[j];
        a0 += __int_as_float(p.y) * x[(size_t)(p.x & 0x1FFFF) * N_FEAT + lane];
    }
    out[(size_t)node * N_FEAT + lane] = (a0 + a1) + (a2 + a3);
}

// ---------------- Path C (R1 scatter) ----------------
__global__ __launch_bounds__(256) void gnn_scatter_kernel(
    const float* __restrict__ x, const int* __restrict__ ei,
    const float* __restrict__ w, float* __restrict__ out, int E) {
    int e = blockIdx.x * 4 + (threadIdx.x >> 6);
    int lane = threadIdx.x & 63;
    if (e >= E) return;
    float v = w[e] * x[(size_t)ei[e] * N_FEAT + lane];
    atomicAdd(&out[(size_t)ei[E + e] * N_FEAT + lane], v);
}

static inline size_t align16(size_t v) { return (v + 15) & ~(size_t)15; }

extern "C" void kernel_launch(void* const* d_in, const int* in_sizes, int n_in,
                              void* d_out, int out_size, void* d_ws, size_t ws_size,
                              hipStream_t stream) {
    const float* x   = (const float*)d_in[0];
    const int*   ei  = (const int*)d_in[1];
    const float* w   = (const float*)d_in[2];
    float*       out = (float*)d_out;
    const int E = in_sizes[2];
    char* ws = (char*)d_ws;

    // ---- Path A layout ----
    size_t a_xb   = 0;
    size_t a_stg  = align16(a_xb + (size_t)N_NODES * N_FEAT * 2);
    size_t a_bcur = align16(a_stg + (size_t)A_KB * A_CAP * 8);    // KB ints + ovcnt
    size_t a_ovf  = align16(a_bcur + (size_t)(A_KB + 1) * 4);
    size_t need_a = a_ovf + (size_t)A_OVCAP * 4;

    if (ws_size >= need_a && E == 1250000) {
        ushort* xb    = (ushort*)(ws + a_xb);
        int2*   stg   = (int2*)(ws + a_stg);
        int*    bcur  = (int*)(ws + a_bcur);
        int*    ovcnt = bcur + A_KB;
        int*    ovf   = (int*)(ws + a_ovf);

        hipMemsetAsync(bcur, 0, (size_t)(A_KB + 1) * 4, stream);
        k_castbin<<<NBIN + NCAST, 1024, 0, stream>>>(
            x, xb, ei, w, bcur, stg, ovf, ovcnt, E);
        k_sortgather<<<A_KB, 1024, 0, stream>>>(xb, bcur, stg, out);
        k_ovf<<<16, 256, 0, stream>>>(x, ei, w, ovf, ovcnt, out, E);
        return;
    }

    // ---- Path B layout (R4) ----
    size_t b_bcur  = 0;
    size_t b_boffs = align16(b_bcur + (size_t)KB * 4);
    size_t b_offs  = align16(b_boffs + (size_t)(KB + 1) * 4);
    size_t b_stg   = align16(b_offs + (size_t)(N_NODES + 1) * 4);
    size_t need_b  = b_stg + (size_t)E * 8;

    if (ws_size >= need_b) {
        int*  bcur  = (int*)(ws + b_bcur);
        int*  boffs = (int*)(ws + b_boffs);
        int*  offs  = (int*)(ws + b_offs);
        int2* stg   = (int2*)(ws + b_stg);
        const int nblk = (E + FCHUNK - 1) / FCHUNK;
        hipMemsetAsync(bcur, 0, (size_t)KB * 4, stream);
        k_chist<<<nblk, 256, 0, stream>>>(ei, bcur, E);
        k_cscan<<<1, 256, 0, stream>>>(bcur, boffs);
        k_cbin<<<nblk, 256, 0, stream>>>(ei, w, bcur, stg, E);
        k_csort<<<KB, 256, 0, stream>>>(stg, boffs, offs);
        k_gather<<<(N_NODES + 3) / 4, 256, 0, stream>>>(x, offs, stg, out);
        return;
    }

    // ---- Path C ----
    hipMemsetAsync(d_out, 0, (size_t)out_size * sizeof(float), stream);
    gnn_scatter_kernel<<<(E + 3) / 4, 256, 0, stream>>>(x, ei, w, out, E);
}